// Round 1
// baseline (551.097 us; speedup 1.0000x reference)
//
#include <hip/hip_runtime.h>
#include <cstdint>
#include <cstddef>

// Problem constants
#define B_  16
#define T_  2048
#define DIN 1024
#define DPJ 512
#define DOUT 1024
#define LORD 20
#define M_ROWS (B_ * T_)            // 32768
#define OUT0_ELEMS ((size_t)M_ROWS * DOUT)          // 33554432
#define CACHE_ELEMS ((size_t)B_ * DPJ * (LORD - 1)) // 155648

typedef __bf16 bf16_t;
typedef __bf16 bf16x4 __attribute__((ext_vector_type(4)));
typedef __bf16 bf16x8 __attribute__((ext_vector_type(8)));
typedef float  f32x4  __attribute__((ext_vector_type(4)));

// ---------------------------------------------------------------------------
// async global->LDS, 16B per lane. lds pointer must be wave-uniform; HW puts
// lane i's 16B at lds_base + i*16.
__device__ __forceinline__ void async_load16(const bf16_t* g, bf16_t* lds_base) {
    __builtin_amdgcn_global_load_lds(
        (const __attribute__((address_space(1))) unsigned int*)g,
        (__attribute__((address_space(3))) unsigned int*)lds_base,
        16, 0, 0);
}

// ---------------------------------------------------------------------------
// f32 -> bf16 cast, 4 elems/thread (float4 in, 8B out)
__global__ __launch_bounds__(256) void cast_f32_bf16(
    const float4* __restrict__ in, bf16x4* __restrict__ out, int n4) {
    int i = blockIdx.x * 256 + threadIdx.x;
    if (i < n4) {
        float4 v = in[i];
        bf16x4 o = { (bf16_t)v.x, (bf16_t)v.y, (bf16_t)v.z, (bf16_t)v.w };
        out[i] = o;
    }
}

// K x N f32 (row-major) -> N x K bf16 ("B^T" layout for the GEMM)
__global__ __launch_bounds__(256) void transpose_cast(
    const float* __restrict__ W, bf16_t* __restrict__ Wt, int K, int N) {
    int idx = blockIdx.x * 256 + threadIdx.x;
    if (idx < K * N) {
        int k = idx / N;
        int n = idx - k * N;
        Wt[(size_t)n * K + k] = (bf16_t)W[idx];  // coalesced read, scattered write (tiny)
    }
}

// ---------------------------------------------------------------------------
// bf16 GEMM, C[M,N] = A[M,K] * Bt[N,K]^T.  128x128 tile, BK=64, 256 thr (4 waves),
// each wave does a 64x64 subtile as 4x4 grid of 16x16x32 MFMAs.
// LDS tiles stored in 16B chunks with XOR swizzle: logical (row r, k-chunk j)
// lives at physical chunk r*8 + (j ^ (r&7))  ->  ds_read_b128 is 2-way-conflict
// (free, m136) instead of 16-way at the naive 128B row stride.
// Staging exploits: physical chunk for lane i in call c is (wave*4+c)*64 + i,
// so r&7 == lane>>3 and the swizzled logical chunk is (lane&7)^(lane>>3),
// call-independent.
// EPI==0: store C as bf16.  EPI==1: C_f32 = relu(acc + bias[n]).
template <int EPI>
__global__ __launch_bounds__(256) void gemm_bt(
    const bf16_t* __restrict__ A, const bf16_t* __restrict__ Bt,
    void* __restrict__ Cv, const float* __restrict__ bias,
    const int M, const int N, const int K) {
    __shared__ bf16_t sA[128 * 64];
    __shared__ bf16_t sB[128 * 64];

    const int tid  = threadIdx.x;
    const int lane = tid & 63;
    const int wave = tid >> 6;
    const int row0 = blockIdx.x * 128;   // M tile
    const int col0 = blockIdx.y * 128;   // N tile

    // staging addresses
    const int lr   = lane >> 3;               // row-within-8 for this lane
    const int jsw  = (lane & 7) ^ lr;         // swizzled logical k-chunk
    const bf16_t* gA0 = A  + (size_t)(row0 + wave * 32 + lr) * K + jsw * 8;
    const bf16_t* gB0 = Bt + (size_t)(col0 + wave * 32 + lr) * K + jsw * 8;
    bf16_t* lA0 = sA + wave * 2048;           // (wave*4+c)*512 elems, c added below
    bf16_t* lB0 = sB + wave * 2048;

    // compute-side fragment coords
    const int wm = (wave >> 1) * 64;
    const int wn = (wave & 1) * 64;
    const int fr = lane & 15;                 // m (or n) within 16
    const int fk = lane >> 4;                 // k-chunk within 32-half

    const f32x4 zero = {0.f, 0.f, 0.f, 0.f};
    f32x4 acc[4][4];
#pragma unroll
    for (int mt = 0; mt < 4; ++mt)
#pragma unroll
        for (int nt = 0; nt < 4; ++nt) acc[mt][nt] = zero;

    for (int k0 = 0; k0 < K; k0 += 64) {
        __syncthreads();                      // prior compute done before overwrite
#pragma unroll
        for (int c = 0; c < 4; ++c) {
            async_load16(gA0 + (size_t)c * 8 * K + k0, lA0 + c * 512);
            async_load16(gB0 + (size_t)c * 8 * K + k0, lB0 + c * 512);
        }
        __syncthreads();                      // drains vmcnt before barrier

#pragma unroll
        for (int h = 0; h < 2; ++h) {
            bf16x8 af[4], bfr[4];
#pragma unroll
            for (int mt = 0; mt < 4; ++mt) {
                int r = wm + mt * 16 + fr;
                int j = h * 4 + fk;
                af[mt] = *(const bf16x8*)(sA + r * 64 + ((j ^ (r & 7)) << 3));
            }
#pragma unroll
            for (int nt = 0; nt < 4; ++nt) {
                int r = wn + nt * 16 + fr;
                int j = h * 4 + fk;
                bfr[nt] = *(const bf16x8*)(sB + r * 64 + ((j ^ (r & 7)) << 3));
            }
#pragma unroll
            for (int mt = 0; mt < 4; ++mt)
#pragma unroll
                for (int nt = 0; nt < 4; ++nt)
                    acc[mt][nt] = __builtin_amdgcn_mfma_f32_16x16x32_bf16(
                        af[mt], bfr[nt], acc[mt][nt], 0, 0, 0);
        }
    }

    // epilogue: C/D layout col=lane&15, row=(lane>>4)*4+reg  [m89]
    const int er = row0 + wm + (lane >> 4) * 4;
    const int ec = col0 + wn + (lane & 15);
    if (EPI == 0) {
        bf16_t* C = (bf16_t*)Cv;
#pragma unroll
        for (int mt = 0; mt < 4; ++mt)
#pragma unroll
            for (int nt = 0; nt < 4; ++nt)
#pragma unroll
                for (int rr = 0; rr < 4; ++rr)
                    C[(size_t)(er + mt * 16 + rr) * N + (ec + nt * 16)] =
                        (bf16_t)acc[mt][nt][rr];
    } else {
        float* C = (float*)Cv;
#pragma unroll
        for (int nt = 0; nt < 4; ++nt) {
            float bb = bias[ec + nt * 16];
#pragma unroll
            for (int mt = 0; mt < 4; ++mt)
#pragma unroll
                for (int rr = 0; rr < 4; ++rr) {
                    float v = acc[mt][nt][rr] + bb;
                    C[(size_t)(er + mt * 16 + rr) * N + (ec + nt * 16)] =
                        v > 0.f ? v : 0.f;
                }
        }
    }
}

// ---------------------------------------------------------------------------
// Depthwise causal conv + residual:
// m[b,t,p] = x[b,t,p] + sum_l cw[p,l] * (t-19+l >= 0 ? x[b,t-19+l,p]
//                                                     : in_cache[b,p,t+l])
__global__ __launch_bounds__(256) void dwconv(
    const bf16_t* __restrict__ x, const float* __restrict__ cache,
    const float* __restrict__ cw, bf16_t* __restrict__ m) {
    const int p   = blockIdx.y * 256 + threadIdx.x;  // 0..511
    const int row = blockIdx.x;                       // b*T + t
    const int b   = row >> 11;
    const int t   = row & 2047;
    const bf16_t* xb = x + ((size_t)b << 11) * DPJ + p;

    float sum = (float)xb[(size_t)t * DPJ];
#pragma unroll
    for (int l = 0; l < LORD; ++l) {
        int tau = t - (LORD - 1) + l;
        float v = (tau >= 0) ? (float)xb[(size_t)tau * DPJ]
                             : cache[((size_t)b * DPJ + p) * (LORD - 1) + (tau + LORD - 1)];
        sum += cw[p * LORD + l] * v;
    }
    m[(size_t)row * DPJ + p] = (bf16_t)sum;
}

// out_cache[b,p,j] = x[b, T-19+j, p]
__global__ __launch_bounds__(256) void cache_out(
    const bf16_t* __restrict__ x, float* __restrict__ oc) {
    int idx = blockIdx.x * 256 + threadIdx.x;
    if (idx < (int)CACHE_ELEMS) {
        int b = idx / (DPJ * (LORD - 1));
        int rem = idx % (DPJ * (LORD - 1));
        int p = rem / (LORD - 1);
        int j = rem % (LORD - 1);
        oc[idx] = (float)x[((size_t)(b * T_ + T_ - (LORD - 1) + j)) * DPJ + p];
    }
}

// ---------------------------------------------------------------------------
extern "C" void kernel_launch(void* const* d_in, const int* in_sizes, int n_in,
                              void* d_out, int out_size, void* d_ws, size_t ws_size,
                              hipStream_t stream) {
    const float* input    = (const float*)d_in[0];  // (16,2048,1024)
    const float* in_cache = (const float*)d_in[1];  // (16,512,19)
    const float* W_lin    = (const float*)d_in[2];  // (1024,512)
    const float* conv_w   = (const float*)d_in[3];  // (512,20)
    const float* W_aff    = (const float*)d_in[4];  // (512,1024)
    const float* b_aff    = (const float*)d_in[5];  // (1024,)
    float* out = (float*)d_out;                     // 33554432 + 155648 f32

    // workspace layout (bytes):
    //   [0, 64MB)          inA_bf16 (32768x1024)  -- later reused for m_bf16 (32768x512)
    //   [64MB, +1MB)       W_lin^T bf16 (512x1024)
    //   [65MB, +32MB)      x bf16 (32768x512)
    //   [97MB, +1MB)       W_aff^T bf16 (1024x512)
    char* ws = (char*)d_ws;
    bf16_t* inA   = (bf16_t*)(ws);
    bf16_t* m_buf = (bf16_t*)(ws);                        // aliases inA (safe: stream-ordered)
    bf16_t* WlinT = (bf16_t*)(ws + 67108864);
    bf16_t* x_buf = (bf16_t*)(ws + 67108864 + 1048576);
    bf16_t* WaffT = (bf16_t*)(ws + 67108864 + 1048576 + 33554432);

    // 1. casts
    cast_f32_bf16<<<32768, 256, 0, stream>>>((const float4*)input, (bf16x4*)inA,
                                             (int)(OUT0_ELEMS / 4) /* 8388608 */);
    transpose_cast<<<(DIN * DPJ + 255) / 256, 256, 0, stream>>>(W_lin, WlinT, DIN, DPJ);
    transpose_cast<<<(DPJ * DOUT + 255) / 256, 256, 0, stream>>>(W_aff, WaffT, DPJ, DOUT);

    // 2. x = input @ W_lin   (M=32768, N=512, K=1024), bf16 out
    gemm_bt<0><<<dim3(M_ROWS / 128, DPJ / 128), 256, 0, stream>>>(
        inA, WlinT, (void*)x_buf, nullptr, M_ROWS, DPJ, DIN);

    // 3. depthwise conv + residual -> m ; out_cache
    dwconv<<<dim3(M_ROWS, DPJ / 256), 256, 0, stream>>>(x_buf, in_cache, conv_w, m_buf);
    cache_out<<<(int)((CACHE_ELEMS + 255) / 256), 256, 0, stream>>>(
        x_buf, out + OUT0_ELEMS);

    // 4. out = relu(m @ W_aff + b)  (M=32768, N=1024, K=512), f32 out
    gemm_bt<1><<<dim3(M_ROWS / 128, DOUT / 128), 256, 0, stream>>>(
        m_buf, WaffT, (void*)out, b_aff, M_ROWS, DOUT, DPJ);
}

// Round 2
// 384.158 us; speedup vs baseline: 1.4346x; 1.4346x over previous
//
#include <hip/hip_runtime.h>
#include <cstdint>
#include <cstddef>

// Problem constants
#define B_  16
#define T_  2048
#define DIN 1024
#define DPJ 512
#define DOUT 1024
#define LORD 20
#define HALO (LORD - 1)             // 19
#define M_ROWS (B_ * T_)            // 32768
#define OUT0_ELEMS ((size_t)M_ROWS * DOUT)          // 33554432
#define CACHE_ELEMS ((size_t)B_ * DPJ * (LORD - 1)) // 155648

typedef __bf16 bf16_t;
typedef __bf16 bf16x2 __attribute__((ext_vector_type(2)));
typedef __bf16 bf16x4 __attribute__((ext_vector_type(4)));
typedef __bf16 bf16x8 __attribute__((ext_vector_type(8)));
typedef float  f32x4  __attribute__((ext_vector_type(4)));

// ---------------------------------------------------------------------------
// async global->LDS, 16B per lane. lds pointer must be wave-uniform; HW puts
// lane i's 16B at lds_base + i*16.
__device__ __forceinline__ void async_load16(const bf16_t* g, bf16_t* lds_base) {
    __builtin_amdgcn_global_load_lds(
        (const __attribute__((address_space(1))) unsigned int*)g,
        (__attribute__((address_space(3))) unsigned int*)lds_base,
        16, 0, 0);
}

// ---------------------------------------------------------------------------
// f32 -> bf16 cast, 4 elems/thread (float4 in, 8B out)
__global__ __launch_bounds__(256) void cast_f32_bf16(
    const float4* __restrict__ in, bf16x4* __restrict__ out, int n4) {
    int i = blockIdx.x * 256 + threadIdx.x;
    if (i < n4) {
        float4 v = in[i];
        bf16x4 o = { (bf16_t)v.x, (bf16_t)v.y, (bf16_t)v.z, (bf16_t)v.w };
        out[i] = o;
    }
}

// K x N f32 (row-major) -> N x K bf16 ("B^T" layout for the GEMM)
__global__ __launch_bounds__(256) void transpose_cast(
    const float* __restrict__ W, bf16_t* __restrict__ Wt, int K, int N) {
    int idx = blockIdx.x * 256 + threadIdx.x;
    if (idx < K * N) {
        int k = idx / N;
        int n = idx - k * N;
        Wt[(size_t)n * K + k] = (bf16_t)W[idx];  // coalesced read, scattered write (tiny)
    }
}

// ---------------------------------------------------------------------------
// bf16 GEMM, C[M,N] = A[M,K] * Bt[N,K]^T.  128x128 tile, BK=64, 256 thr (4 waves),
// each wave does a 64x64 subtile as 4x4 grid of 16x16x32 MFMAs.
// LDS tiles stored in 16B chunks with XOR swizzle: logical (row r, k-chunk j)
// lives at physical chunk r*8 + (j ^ (r&7))  ->  ds_read_b128 is 2-way-conflict
// (free, m136) instead of 16-way at the naive 128B row stride.
// EPI==0: store C as bf16.  EPI==1: C_f32 = relu(acc + bias[n]).
template <int EPI>
__global__ __launch_bounds__(256) void gemm_bt(
    const bf16_t* __restrict__ A, const bf16_t* __restrict__ Bt,
    void* __restrict__ Cv, const float* __restrict__ bias,
    const int M, const int N, const int K) {
    __shared__ bf16_t sA[128 * 64];
    __shared__ bf16_t sB[128 * 64];

    const int tid  = threadIdx.x;
    const int lane = tid & 63;
    const int wave = tid >> 6;
    const int row0 = blockIdx.x * 128;   // M tile
    const int col0 = blockIdx.y * 128;   // N tile

    // staging addresses
    const int lr   = lane >> 3;               // row-within-8 for this lane
    const int jsw  = (lane & 7) ^ lr;         // swizzled logical k-chunk
    const bf16_t* gA0 = A  + (size_t)(row0 + wave * 32 + lr) * K + jsw * 8;
    const bf16_t* gB0 = Bt + (size_t)(col0 + wave * 32 + lr) * K + jsw * 8;
    bf16_t* lA0 = sA + wave * 2048;
    bf16_t* lB0 = sB + wave * 2048;

    // compute-side fragment coords
    const int wm = (wave >> 1) * 64;
    const int wn = (wave & 1) * 64;
    const int fr = lane & 15;                 // m (or n) within 16
    const int fk = lane >> 4;                 // k-chunk within 32-half

    const f32x4 zero = {0.f, 0.f, 0.f, 0.f};
    f32x4 acc[4][4];
#pragma unroll
    for (int mt = 0; mt < 4; ++mt)
#pragma unroll
        for (int nt = 0; nt < 4; ++nt) acc[mt][nt] = zero;

    for (int k0 = 0; k0 < K; k0 += 64) {
        __syncthreads();                      // prior compute done before overwrite
#pragma unroll
        for (int c = 0; c < 4; ++c) {
            async_load16(gA0 + (size_t)c * 8 * K + k0, lA0 + c * 512);
            async_load16(gB0 + (size_t)c * 8 * K + k0, lB0 + c * 512);
        }
        __syncthreads();                      // drains vmcnt before barrier

#pragma unroll
        for (int h = 0; h < 2; ++h) {
            bf16x8 af[4], bfr[4];
#pragma unroll
            for (int mt = 0; mt < 4; ++mt) {
                int r = wm + mt * 16 + fr;
                int j = h * 4 + fk;
                af[mt] = *(const bf16x8*)(sA + r * 64 + ((j ^ (r & 7)) << 3));
            }
#pragma unroll
            for (int nt = 0; nt < 4; ++nt) {
                int r = wn + nt * 16 + fr;
                int j = h * 4 + fk;
                bfr[nt] = *(const bf16x8*)(sB + r * 64 + ((j ^ (r & 7)) << 3));
            }
#pragma unroll
            for (int mt = 0; mt < 4; ++mt)
#pragma unroll
                for (int nt = 0; nt < 4; ++nt)
                    acc[mt][nt] = __builtin_amdgcn_mfma_f32_16x16x32_bf16(
                        af[mt], bfr[nt], acc[mt][nt], 0, 0, 0);
        }
    }

    // epilogue: C/D layout col=lane&15, row=(lane>>4)*4+reg  [m89]
    const int er = row0 + wm + (lane >> 4) * 4;
    const int ec = col0 + wn + (lane & 15);
    if (EPI == 0) {
        bf16_t* C = (bf16_t*)Cv;
#pragma unroll
        for (int mt = 0; mt < 4; ++mt)
#pragma unroll
            for (int nt = 0; nt < 4; ++nt)
#pragma unroll
                for (int rr = 0; rr < 4; ++rr)
                    C[(size_t)(er + mt * 16 + rr) * N + (ec + nt * 16)] =
                        (bf16_t)acc[mt][nt][rr];
    } else {
        float* C = (float*)Cv;
#pragma unroll
        for (int nt = 0; nt < 4; ++nt) {
            float bb = bias[ec + nt * 16];
#pragma unroll
            for (int mt = 0; mt < 4; ++mt)
#pragma unroll
                for (int rr = 0; rr < 4; ++rr) {
                    float v = acc[mt][nt][rr] + bb;
                    C[(size_t)(er + mt * 16 + rr) * N + (ec + nt * 16)] =
                        v > 0.f ? v : 0.f;
                }
        }
    }
}

// ---------------------------------------------------------------------------
// Depthwise causal conv + residual, LDS-tiled with rolling register window.
// m[b,t,p] = x[b,t,p] + sum_l cw[p,l] * window(t,l)
// Tile: TT=64 timesteps x PP=128 channels per block; stage (TT+19) x 128 x f32
// in LDS (coalesced bf16x8 global loads), each thread owns a float2 channel
// pair + 16 timesteps, reading each LDS value exactly once via a 20-deep
// rolling register window (float2 -> packed fma).
#define TT 64
#define PPT 128
__global__ __launch_bounds__(256) void dwconv_tiled(
    const bf16_t* __restrict__ x, const float* __restrict__ cache,
    const float* __restrict__ cw, bf16_t* __restrict__ m) {
    __shared__ float sx[(TT + HALO) * PPT];   // 83*128*4 = 42.5 KB

    const int tid = threadIdx.x;
    const int t0  = blockIdx.x * TT;
    const int b   = blockIdx.y;
    const int p0  = blockIdx.z * PPT;

    // ---- stage rows t0-19 .. t0+63, cols p0..p0+127 (8 bf16 per chunk) ----
    for (int c = tid; c < (TT + HALO) * PPT / 8; c += 256) {   // 1328 chunks
        int r    = c >> 4;            // 0..82
        int col  = (c & 15) << 3;     // 0,8,...,120
        int trow = t0 - HALO + r;
        float* dst = sx + r * PPT + col;
        if (trow >= 0) {
            bf16x8 v = *(const bf16x8*)(x + ((size_t)(b * T_ + trow)) * DPJ + p0 + col);
#pragma unroll
            for (int i = 0; i < 8; ++i) dst[i] = (float)v[i];
        } else {
            // in_cache[b, p, j] layout (b, DPJ, 19); j = trow + 19
#pragma unroll
            for (int i = 0; i < 8; ++i)
                dst[i] = cache[((size_t)b * DPJ + p0 + col + i) * HALO + (trow + HALO)];
        }
    }
    __syncthreads();

    // ---- compute: thread -> channel pair pp (p = p0+2*pp, +1), 16 timesteps ----
    const int pp   = tid & 63;        // float2 column 0..63
    const int half = tid >> 6;        // 0..3
    const int tb   = half * 16;       // local t base
    const float2* sx2 = (const float2*)sx;   // [83][64]

    const int pg = p0 + 2 * pp;
    float2 w[LORD];
#pragma unroll
    for (int l = 0; l < LORD; ++l) {
        w[l].x = cw[pg * LORD + l];
        w[l].y = cw[(pg + 1) * LORD + l];
    }

    // rolling window: win[(tl+l)%LORD] holds conv row tb+tl+l
    float2 win[LORD];
#pragma unroll
    for (int i = 0; i < HALO; ++i) win[i] = sx2[(tb + i) * 64 + pp];

#pragma unroll
    for (int tl = 0; tl < 16; ++tl) {
        float2 nv = sx2[(tb + tl + HALO) * 64 + pp];
        win[(tl + HALO) % LORD] = nv;
        float2 s = nv;                         // residual x[b,t,p]
#pragma unroll
        for (int l = 0; l < LORD; ++l) {
            float2 v = win[(tl + l) % LORD];
            s.x += w[l].x * v.x;
            s.y += w[l].y * v.y;
        }
        bf16x2 o = { (bf16_t)s.x, (bf16_t)s.y };
        *(bf16x2*)(m + ((size_t)(b * T_ + t0 + tb + tl)) * DPJ + pg) = o;
    }
}

// out_cache[b,p,j] = x[b, T-19+j, p]
__global__ __launch_bounds__(256) void cache_out(
    const bf16_t* __restrict__ x, float* __restrict__ oc) {
    int idx = blockIdx.x * 256 + threadIdx.x;
    if (idx < (int)CACHE_ELEMS) {
        int b = idx / (DPJ * (LORD - 1));
        int rem = idx % (DPJ * (LORD - 1));
        int p = rem / (LORD - 1);
        int j = rem % (LORD - 1);
        oc[idx] = (float)x[((size_t)(b * T_ + T_ - (LORD - 1) + j)) * DPJ + p];
    }
}

// ---------------------------------------------------------------------------
extern "C" void kernel_launch(void* const* d_in, const int* in_sizes, int n_in,
                              void* d_out, int out_size, void* d_ws, size_t ws_size,
                              hipStream_t stream) {
    const float* input    = (const float*)d_in[0];  // (16,2048,1024)
    const float* in_cache = (const float*)d_in[1];  // (16,512,19)
    const float* W_lin    = (const float*)d_in[2];  // (1024,512)
    const float* conv_w   = (const float*)d_in[3];  // (512,20)
    const float* W_aff    = (const float*)d_in[4];  // (512,1024)
    const float* b_aff    = (const float*)d_in[5];  // (1024,)
    float* out = (float*)d_out;                     // 33554432 + 155648 f32

    // workspace layout (bytes):
    //   [0, 64MB)          inA_bf16 (32768x1024)  -- later reused for m_bf16 (32768x512)
    //   [64MB, +1MB)       W_lin^T bf16 (512x1024)
    //   [65MB, +32MB)      x bf16 (32768x512)
    //   [97MB, +1MB)       W_aff^T bf16 (1024x512)
    char* ws = (char*)d_ws;
    bf16_t* inA   = (bf16_t*)(ws);
    bf16_t* m_buf = (bf16_t*)(ws);                  // aliases inA (stream-ordered, safe)
    bf16_t* WlinT = (bf16_t*)(ws + 67108864);
    bf16_t* x_buf = (bf16_t*)(ws + 67108864 + 1048576);
    bf16_t* WaffT = (bf16_t*)(ws + 67108864 + 1048576 + 33554432);

    // 1. casts
    cast_f32_bf16<<<32768, 256, 0, stream>>>((const float4*)input, (bf16x4*)inA,
                                             (int)(OUT0_ELEMS / 4));
    transpose_cast<<<(DIN * DPJ + 255) / 256, 256, 0, stream>>>(W_lin, WlinT, DIN, DPJ);
    transpose_cast<<<(DPJ * DOUT + 255) / 256, 256, 0, stream>>>(W_aff, WaffT, DPJ, DOUT);

    // 2. x = input @ W_lin   (M=32768, N=512, K=1024), bf16 out
    gemm_bt<0><<<dim3(M_ROWS / 128, DPJ / 128), 256, 0, stream>>>(
        inA, WlinT, (void*)x_buf, nullptr, M_ROWS, DPJ, DIN);

    // 3. depthwise conv + residual -> m ; out_cache
    dwconv_tiled<<<dim3(T_ / TT, B_, DPJ / PPT), 256, 0, stream>>>(
        x_buf, in_cache, conv_w, m_buf);
    cache_out<<<(int)((CACHE_ELEMS + 255) / 256), 256, 0, stream>>>(
        x_buf, out + OUT0_ELEMS);

    // 4. out = relu(m @ W_aff + b)  (M=32768, N=1024, K=512), f32 out
    gemm_bt<1><<<dim3(M_ROWS / 128, DOUT / 128), 256, 0, stream>>>(
        m_buf, WaffT, (void*)out, b_aff, M_ROWS, DOUT, DPJ);
}